// Round 18
// baseline (462.726 us; speedup 1.0000x reference)
//
#include <hip/hip_runtime.h>
#include <hip/hip_bf16.h>

#define B_SEG 65536
#define N_NODES 1048576

typedef _Float16 f16;
typedef __attribute__((ext_vector_type(8))) _Float16 f16x8;
typedef __attribute__((ext_vector_type(2))) __fp16 fp16x2;   // cvt_pkrtz's return type
typedef __attribute__((ext_vector_type(4))) float f32x4;
typedef unsigned short u16;

union F16x8 { f16x8 v; fp16x2 h2[4]; };

#define MFMA16(a, b, acc) __builtin_amdgcn_mfma_f32_16x16x32_f16((a), (b), (acc), 0, 0, 0)

typedef __attribute__((address_space(1))) const void GV;
typedef __attribute__((address_space(3))) void LV;
#define GLOAD_LDS16(g, l) __builtin_amdgcn_global_load_lds((GV*)(g), (LV*)(l), 16, 0, 0)

// ---------------- histogram + rank capture, XCD-partitioned ----------------
__global__ __launch_bounds__(256) void histo_part(const int* __restrict__ idx0,
        const int* __restrict__ idx1, int* __restrict__ cnt0, int* __restrict__ cnt1,
        u16* __restrict__ rankp0, u16* __restrict__ rankp1) {
    int part  = blockIdx.x & 7;
    int chunk = blockIdx.x >> 3;              // 0..255
    u16* r0 = rankp0 + (size_t)part * N_NODES;
    u16* r1 = rankp1 + (size_t)part * N_NODES;
    int base4 = chunk * (N_NODES / 256 / 4);  // 1024 int4-groups per chunk
    for (int g = base4 + threadIdx.x; g < base4 + N_NODES / 256 / 4; g += 256) {
        int4 s0 = ((const int4*)idx0)[g];
        int i = g * 4;
        if ((s0.x >> 13) == part) { int p = atomicAdd(&cnt0[s0.x], 1); r0[i]     = (u16)p; }
        if ((s0.y >> 13) == part) { int p = atomicAdd(&cnt0[s0.y], 1); r0[i + 1] = (u16)p; }
        if ((s0.z >> 13) == part) { int p = atomicAdd(&cnt0[s0.z], 1); r0[i + 2] = (u16)p; }
        if ((s0.w >> 13) == part) { int p = atomicAdd(&cnt0[s0.w], 1); r0[i + 3] = (u16)p; }
        int4 s1 = ((const int4*)idx1)[g];
        if ((s1.x >> 13) == part) { int p = atomicAdd(&cnt1[s1.x], 1); r1[i]     = (u16)p; }
        if ((s1.y >> 13) == part) { int p = atomicAdd(&cnt1[s1.y], 1); r1[i + 1] = (u16)p; }
        if ((s1.z >> 13) == part) { int p = atomicAdd(&cnt1[s1.z], 1); r1[i + 2] = (u16)p; }
        if ((s1.w >> 13) == part) { int p = atomicAdd(&cnt1[s1.w], 1); r1[i + 3] = (u16)p; }
    }
}

// ---------------- 3-stage scan over 2x65536 counters ----------------
__global__ __launch_bounds__(256) void scan1(const int* __restrict__ cnt, int* __restrict__ bsum) {
    int b = blockIdx.x, t = threadIdx.x;
    int4 v = ((const int4*)cnt)[b * 256 + t];
    int s = v.x + v.y + v.z + v.w;
    for (int d = 1; d < 64; d <<= 1) s += __shfl_xor(s, d);
    __shared__ int ws4[4];
    if ((t & 63) == 0) ws4[t >> 6] = s;
    __syncthreads();
    if (t == 0) bsum[b] = ws4[0] + ws4[1] + ws4[2] + ws4[3];
}

__global__ __launch_bounds__(128) void scan2(int* __restrict__ bsum) {
    int t = threadIdx.x, lane = t & 63;
    int v = bsum[t];
    int s = v;
    for (int d = 1; d < 64; d <<= 1) { int u = __shfl_up(s, d); if (lane >= d) s += u; }
    bsum[t] = s - v;
}

__global__ __launch_bounds__(256) void scan3(const int* __restrict__ cnt, const int* __restrict__ bsum,
                                             int* __restrict__ off0, int* __restrict__ off1) {
    int b = blockIdx.x, t = threadIdx.x;
    int4 v = ((const int4*)cnt)[b * 256 + t];
    int local = v.x + v.y + v.z + v.w;
    int lane = t & 63, w = t >> 6;
    int s = local;
    for (int d = 1; d < 64; d <<= 1) { int u = __shfl_up(s, d); if (lane >= d) s += u; }
    __shared__ int wsum[4];
    if (lane == 63) wsum[w] = s;
    __syncthreads();
    int carry = bsum[b];
    for (int i = 0; i < w; ++i) carry += wsum[i];
    int ex = carry + s - local;
    int* off = (b < 64) ? off0 : off1;
    int gi = (b & 63) * 1024 + t * 4;
    off[gi] = ex; ex += v.x; off[gi + 1] = ex; ex += v.y; off[gi + 2] = ex; ex += v.z; off[gi + 3] = ex;
    if (b == 0 && t == 0) { off0[B_SEG] = N_NODES; off1[B_SEG] = N_NODES; }
}

// ---------------- fill CSR (partitioned, zero atomics) + fused weight prep ----------------
__global__ __launch_bounds__(256) void fill_prep(const int* __restrict__ idx0,
        const int* __restrict__ idx1, const u16* __restrict__ rankp0, const u16* __restrict__ rankp1,
        const int* __restrict__ off0, const int* __restrict__ off1,
        int* __restrict__ ord0, int* __restrict__ ord1,
        const float* __restrict__ Wc0, const float* __restrict__ Wc1,
        const float* __restrict__ Wb1, const float* __restrict__ Wb2,
        f16* __restrict__ T0, f16* __restrict__ T1, f16* __restrict__ T2, f16* __restrict__ T3) {
    if (blockIdx.x < 2048) {
        int part  = blockIdx.x & 7;
        int chunk = blockIdx.x >> 3;
        const u16* r0 = rankp0 + (size_t)part * N_NODES;
        const u16* r1 = rankp1 + (size_t)part * N_NODES;
        int base4 = chunk * (N_NODES / 256 / 4);
        for (int g = base4 + threadIdx.x; g < base4 + N_NODES / 256 / 4; g += 256) {
            int4 s0 = ((const int4*)idx0)[g];
            ushort4 q0 = ((const ushort4*)r0)[g];
            int i = g * 4;
            if ((s0.x >> 13) == part) ord0[off0[s0.x] + q0.x] = i;
            if ((s0.y >> 13) == part) ord0[off0[s0.y] + q0.y] = i + 1;
            if ((s0.z >> 13) == part) ord0[off0[s0.z] + q0.z] = i + 2;
            if ((s0.w >> 13) == part) ord0[off0[s0.w] + q0.w] = i + 3;
            int4 s1 = ((const int4*)idx1)[g];
            ushort4 q1 = ((const ushort4*)r1)[g];
            if ((s1.x >> 13) == part) ord1[off1[s1.x] + q1.x] = i;
            if ((s1.y >> 13) == part) ord1[off1[s1.y] + q1.y] = i + 1;
            if ((s1.z >> 13) == part) ord1[off1[s1.z] + q1.z] = i + 2;
            if ((s1.w >> 13) == part) ord1[off1[s1.w] + q1.w] = i + 3;
        }
    } else {
        int b = blockIdx.x - 2048, t = threadIdx.x;
        if (b < 64)        { int i = b * 256 + t;         T0[i] = (f16)Wc0[(i & 127) * 128 + (i >> 7)]; }
        else if (b < 128)  { int i = (b - 64) * 256 + t;  T1[i] = (f16)Wc1[(i & 127) * 128 + (i >> 7)]; }
        else if (b < 384)  { int i = (b - 128) * 256 + t; T2[i] = (f16)Wb1[(i & 255) * 256 + (i >> 8)]; }
        else               { int i = (b - 384) * 256 + t; T3[i] = (f16)Wb2[(i & 255) * 128 + (i >> 8)]; }
    }
}

// ---------------- per-segment mean of relu(x@Wr+br): LDS-ring deep pipeline ----------------
// Flat item schedule (r9/r10 machinery, correctness-proven) + DEPTH=3 LDS ring
// per wave filled by global_load_lds (16B/lane, dest = uniform base + lane*16,
// matching the per-lane read-back exactly). Counted inline-asm vmcnt(8) keeps
// 2 items (8 loads) in flight across iterations -- depth without VGPR cost.
// FIFO safety: extra outstanding ops (ord-fallback loads, means stores) only
// make the wait stricter. Invalid lanes clamp node->0 at issue; fragments
// zeroed by select at read. Wave-private slots -> no barriers.
#define SEGS_PER_WAVE 8
#define DEPTH 3
__global__ __launch_bounds__(256, 3) void eye_means_mfma(
        const float* __restrict__ xA, const float* __restrict__ WrA, const float* __restrict__ brA,
        const int* __restrict__ offA, const int* __restrict__ ordA, f16* __restrict__ meansA,
        const float* __restrict__ xB, const float* __restrict__ WrB, const float* __restrict__ brB,
        const int* __restrict__ offB, const int* __restrict__ ordB, f16* __restrict__ meansB) {
    const float *x, *Wr, *br; const int *off, *ord; f16* means;
    if (blockIdx.y == 0) { x = xA; Wr = WrA; br = brA; off = offA; ord = ordA; means = meansA; }
    else                 { x = xB; Wr = WrB; br = brB; off = offB; ord = ordB; means = meansB; }

    __shared__ char ldsraw[4][DEPTH][4096];
    int lane = threadIdx.x & 63;
    int wv   = threadIdx.x >> 6;
    int wid  = blockIdx.x * 4 + wv;
    int c  = lane & 15;    // A row / C col within tile
    int kq = lane >> 4;    // k-quarter
    char* myslots = &ldsraw[wv][0][0];

    // B fragments: bfr[g][h] covers cols g*16..+15, k = h*32 + kq*8 .. +7
    f16x8 bfr[8][2];
    float rbias[8];
    #pragma unroll
    for (int g = 0; g < 8; ++g) {
        #pragma unroll
        for (int h = 0; h < 2; ++h)
            #pragma unroll
            for (int j = 0; j < 8; ++j)
                bfr[g][h][j] = (f16)Wr[(size_t)(h * 32 + kq * 8 + j) * 128 + g * 16 + c];
        rbias[g] = br[g * 16 + c];
    }

    int s_begin = wid * SEGS_PER_WAVE;
    int offv  = off[s_begin + ((lane <= 8) ? lane : 8)];     // lane i<=8: off[s_begin+i]
    int base0 = __shfl(offv, 0);
    int nxtv  = __shfl(offv, (lane < 8) ? (lane + 1) : 8);
    int szl   = nxtv - offv;             // lanes 0..7: size of segment i
    int nbl   = (szl + 15) >> 4;         // lanes 0..7: batch count of segment i

    // pooled CSR preload: entries base0..base0+191 (mean 128, ~5.7 sigma)
    int ov0 = ord[base0 + lane];
    int ov1 = ord[base0 + 64 + lane];
    int ov2 = ord[base0 + 128 + lane];

    int totalNB = 0;
    #pragma unroll
    for (int s = 0; s < 8; ++s) totalNB += __shfl(nbl, s);

    // pool entry -> node id; all shfls unconditional, uniform flow
    auto pool_fetch = [&](int ei) -> int {
        int e6 = ei & 63;
        int n0 = __shfl(ov0, e6);
        int n1 = __shfl(ov1, e6);
        int n2 = __shfl(ov2, e6);
        int n  = (ei < 64) ? n0 : (ei < 128) ? n1 : n2;
        if (ei >= 192) n = ord[base0 + ei];   // stays within ws (ord padded; r9/r10 precedent)
        return n;
    };

    float sum[8];
    #pragma unroll
    for (int g = 0; g < 8; ++g) sum[g] = 0.f;
    const f16x8 zf = {};

    int e = 0;
    while (e < totalNB) {                         // chunk loop (1 iter in practice)
        int chunk_n = totalNB - e;
        if (chunk_n > 64) chunk_n = 64;

        // lane-table: lane el describes batch item e+el (uniform flow)
        int bb = e + lane;
        int cum = 0, s_of = 7, b_of = 0;
        bool found = false;
        #pragma unroll
        for (int s = 0; s < 8; ++s) {
            int nbs = __shfl(nbl, s);
            if (!found && bb < cum + nbs) { s_of = s; b_of = bb - cum; found = true; }
            cum += nbs;
        }
        int offs  = __shfl(offv, s_of) - base0;
        int szs   = __shfl(szl, s_of);
        int rs_t  = offs + b_of * 16;             // pool index of this item's row 0
        int ren_t = offs + szs;                   // pool index of segment end
        int sg_t  = s_of;

        // issue item el's 4 gathers into LDS slot (16B per lane per chunk)
        auto issue_item = [&](int el, int slot) {
            int rs  = __shfl(rs_t,  el & 63);
            int ren = __shfl(ren_t, el & 63);
            int ei  = rs + c;
            int n   = pool_fetch(ei);
            int node = (ei < ren) ? n : 0;        // clamp invalid to safe address
            const float* xp = &x[(size_t)node * 64 + kq * 8];
            char* lb = myslots + slot * 4096;
            GLOAD_LDS16(xp,      lb);
            GLOAD_LDS16(xp + 4,  lb + 1024);
            GLOAD_LDS16(xp + 32, lb + 2048);
            GLOAD_LDS16(xp + 36, lb + 3072);
        };

        // compute item el from LDS slot; flush its segment if last batch
        auto do_item = [&](int el, int slot) {
            int rsX  = __shfl(rs_t,  el & 63);
            int renX = __shfl(ren_t, el & 63);
            asm volatile("s_waitcnt vmcnt(8)" ::: "memory");   // item el's 4 loads done
            __builtin_amdgcn_sched_barrier(0);
            const float4* sp = (const float4*)(myslots + slot * 4096);
            float4 va = sp[lane];
            float4 vb = sp[64 + lane];
            float4 vc = sp[128 + lane];
            float4 vd = sp[192 + lane];
            bool valid = (rsX + c < renX);
            f16x8 A0 = zf, A1 = zf;
            if (valid) {
                F16x8 u0, u1;
                u0.h2[0] = __builtin_amdgcn_cvt_pkrtz(va.x, va.y);
                u0.h2[1] = __builtin_amdgcn_cvt_pkrtz(va.z, va.w);
                u0.h2[2] = __builtin_amdgcn_cvt_pkrtz(vb.x, vb.y);
                u0.h2[3] = __builtin_amdgcn_cvt_pkrtz(vb.z, vb.w);
                u1.h2[0] = __builtin_amdgcn_cvt_pkrtz(vc.x, vc.y);
                u1.h2[1] = __builtin_amdgcn_cvt_pkrtz(vc.z, vc.w);
                u1.h2[2] = __builtin_amdgcn_cvt_pkrtz(vd.x, vd.y);
                u1.h2[3] = __builtin_amdgcn_cvt_pkrtz(vd.z, vd.w);
                A0 = u0.v; A1 = u1.v;
            }
            #pragma unroll
            for (int g = 0; g < 8; ++g) {
                f32x4 acc = {0.f, 0.f, 0.f, 0.f};
                acc = MFMA16(A0, bfr[g][0], acc);
                acc = MFMA16(A1, bfr[g][1], acc);
                #pragma unroll
                for (int r = 0; r < 4; ++r)
                    sum[g] += fmaxf(acc[r] + rbias[g], 0.f);   // relu BEFORE segment sum
            }
            if (renX - rsX <= 16) {               // wave-uniform: segment's last batch
                int sg  = __shfl(sg_t, el & 63);
                int szS = __shfl(szl, sg);
                int nbS = __shfl(nbl, sg);
                float padc = (float)(nbS * 16 - szS);
                float inv  = 1.f / (float)szS;
                size_t mb  = (size_t)(s_begin + sg) * 128;
                #pragma unroll
                for (int g = 0; g < 8; ++g) {
                    float v = sum[g];
                    v += __shfl_xor(v, 16);
                    v += __shfl_xor(v, 32);
                    v -= padc * fmaxf(rbias[g], 0.f);   // padded rows contributed relu(bias)
                    sum[g] = v * inv;
                }
                means[mb + (2 * kq + 0) * 16 + c] = (f16)sum[2 * kq + 0];
                means[mb + (2 * kq + 1) * 16 + c] = (f16)sum[2 * kq + 1];
                #pragma unroll
                for (int g = 0; g < 8; ++g) sum[g] = 0.f;
            }
        };

        // prologue: items 0,1 -> slots 0,1 (wrap-safe junk if chunk_n small)
        issue_item(0, 0);
        issue_item(1, 1);
        int sI = 2, sC = 0;
        for (int el = 0; el < chunk_n; ++el) {
            issue_item(el + 2, sI);               // junk issues clamp to node 0
            sI = (sI == DEPTH - 1) ? 0 : sI + 1;
            do_item(el, sC);
            sC = (sC == DEPTH - 1) ? 0 : sC + 1;
        }
        asm volatile("s_waitcnt vmcnt(0)" ::: "memory");   // chunk drain
        __builtin_amdgcn_sched_barrier(0);
        e += chunk_n;
    }

    // empty segments -> zero means (uniform shfl, uniform condition)
    #pragma unroll
    for (int s = 0; s < 8; ++s) {
        int szS = __shfl(szl, s);
        if (szS == 0) {
            size_t mb = (size_t)(s_begin + s) * 128;
            means[mb + (2 * kq + 0) * 16 + c] = (f16)0.f;
            means[mb + (2 * kq + 1) * 16 + c] = (f16)0.f;
        }
    }
}

// ---------------- f16 MFMA GEMM, zero-LDS ----------------
template<int K, int RELU, int OUT16>
__global__ __launch_bounds__(256) void gemm16(
        const f16* __restrict__ A, const f16* __restrict__ BT,
        const float* __restrict__ bias, void* __restrict__ Cv, int ldc) {
    int lane = threadIdx.x & 63;
    int w = threadIdx.x >> 6;
    int c = lane & 15, kq = lane >> 4;
    int m0 = blockIdx.x * 128 + w * 32;
    int n0 = blockIdx.y * 128;

    f32x4 acc[2][8] = {};
    const f16* arow0 = A + (size_t)(m0 + c) * K + kq * 8;
    const f16* arow1 = arow0 + (size_t)16 * K;
    const f16* brow  = BT + (size_t)(n0 + c) * K + kq * 8;

    #pragma unroll 2
    for (int k0 = 0; k0 < K; k0 += 32) {
        f16x8 a0 = *(const f16x8*)(arow0 + k0);
        f16x8 a1 = *(const f16x8*)(arow1 + k0);
        #pragma unroll
        for (int g = 0; g < 8; ++g) {
            f16x8 bf = *(const f16x8*)(brow + (size_t)g * 16 * K + k0);
            acc[0][g] = MFMA16(a0, bf, acc[0][g]);
            acc[1][g] = MFMA16(a1, bf, acc[1][g]);
        }
    }

    #pragma unroll
    for (int g = 0; g < 8; ++g) {
        float bv = bias[n0 + g * 16 + c];
        #pragma unroll
        for (int ms = 0; ms < 2; ++ms) {
            #pragma unroll
            for (int r = 0; r < 4; ++r) {
                float v = acc[ms][g][r] + bv;
                if (RELU) v = fmaxf(v, 0.f);
                size_t ci = (size_t)(m0 + ms * 16 + kq * 4 + r) * ldc + n0 + g * 16 + c;
                if (OUT16) ((f16*)Cv)[ci] = (f16)v;
                else       ((float*)Cv)[ci] = v;
            }
        }
    }
}

// Wc stage for both eyes in one launch
__global__ __launch_bounds__(256) void gemm_wc(
        const f16* __restrict__ M0, const f16* __restrict__ M1,
        const f16* __restrict__ T0, const f16* __restrict__ T1,
        const float* __restrict__ bc0, const float* __restrict__ bc1,
        f16* __restrict__ z) {
    int e = blockIdx.y;
    const f16* A  = e ? M1 : M0;
    const f16* BT = e ? T1 : T0;
    const float* bias = e ? bc1 : bc0;
    int lane = threadIdx.x & 63;
    int w = threadIdx.x >> 6;
    int c = lane & 15, kq = lane >> 4;
    int m0 = blockIdx.x * 128 + w * 32;

    f32x4 acc[2][8] = {};
    const f16* arow0 = A + (size_t)(m0 + c) * 128 + kq * 8;
    const f16* arow1 = arow0 + (size_t)16 * 128;
    const f16* brow  = BT + (size_t)c * 128 + kq * 8;

    #pragma unroll
    for (int k0 = 0; k0 < 128; k0 += 32) {
        f16x8 a0 = *(const f16x8*)(arow0 + k0);
        f16x8 a1 = *(const f16x8*)(arow1 + k0);
        #pragma unroll
        for (int g = 0; g < 8; ++g) {
            f16x8 bf = *(const f16x8*)(brow + (size_t)g * 16 * 128 + k0);
            acc[0][g] = MFMA16(a0, bf, acc[0][g]);
            acc[1][g] = MFMA16(a1, bf, acc[1][g]);
        }
    }

    #pragma unroll
    for (int g = 0; g < 8; ++g) {
        float bv = bias[g * 16 + c];
        #pragma unroll
        for (int ms = 0; ms < 2; ++ms) {
            #pragma unroll
            for (int r = 0; r < 4; ++r) {
                float v = fmaxf(acc[ms][g][r] + bv, 0.f);
                z[(size_t)(m0 + ms * 16 + kq * 4 + r) * 256 + e * 128 + g * 16 + c] = (f16)v;
            }
        }
    }
}

extern "C" void kernel_launch(void* const* d_in, const int* in_sizes, int n_in,
                              void* d_out, int out_size, void* d_ws, size_t ws_size,
                              hipStream_t stream) {
    const float* x0  = (const float*)d_in[0];
    const float* x1  = (const float*)d_in[1];
    const int*   idx0 = (const int*)d_in[2];
    const int*   idx1 = (const int*)d_in[3];
    const float* Wr0 = (const float*)d_in[4];
    const float* br0 = (const float*)d_in[5];
    const float* Wc0 = (const float*)d_in[6];
    const float* bc0 = (const float*)d_in[7];
    const float* Wr1 = (const float*)d_in[8];
    const float* br1 = (const float*)d_in[9];
    const float* Wc1 = (const float*)d_in[10];
    const float* bc1 = (const float*)d_in[11];
    const float* Wb1 = (const float*)d_in[12];
    const float* bb1 = (const float*)d_in[13];
    const float* Wb2 = (const float*)d_in[14];
    const float* bb2 = (const float*)d_in[15];
    float* out = (float*)d_out;

    char* w = (char*)d_ws;
    auto alloc = [&](size_t bytes) { void* p = (void*)w; w += (bytes + 255) & ~(size_t)255; return p; };
    int* cnt0 = (int*)alloc((size_t)B_SEG * 4);
    int* cnt1 = (int*)alloc((size_t)B_SEG * 4);
    int* off0 = (int*)alloc((size_t)(B_SEG + 1) * 4);
    int* off1 = (int*)alloc((size_t)(B_SEG + 1) * 4);
    int* ord0 = (int*)alloc((size_t)(N_NODES + 4096) * 4);   // generous pad for pool fallback
    int* ord1 = (int*)alloc((size_t)(N_NODES + 4096) * 4);
    u16* rankp0 = (u16*)alloc((size_t)8 * N_NODES * 2);      // per-partition rank slices
    u16* rankp1 = (u16*)alloc((size_t)8 * N_NODES * 2);
    int* bsum = (int*)alloc(128 * 4);
    f16* means0 = (f16*)alloc((size_t)B_SEG * 128 * 2);
    f16* means1 = (f16*)alloc((size_t)B_SEG * 128 * 2);
    f16* z      = (f16*)alloc((size_t)B_SEG * 256 * 2);
    f16* hb     = (f16*)alloc((size_t)B_SEG * 256 * 2);
    f16* T0     = (f16*)alloc((size_t)128 * 128 * 2);
    f16* T1     = (f16*)alloc((size_t)128 * 128 * 2);
    f16* T2     = (f16*)alloc((size_t)256 * 256 * 2);
    f16* T3     = (f16*)alloc((size_t)128 * 256 * 2);

    (void)hipMemsetAsync(cnt0, 0, 2 * (size_t)B_SEG * sizeof(int), stream);
    histo_part<<<2048, 256, 0, stream>>>(idx0, idx1, cnt0, cnt1, rankp0, rankp1);
    scan1<<<128, 256, 0, stream>>>(cnt0, bsum);
    scan2<<<1, 128, 0, stream>>>(bsum);
    scan3<<<128, 256, 0, stream>>>(cnt0, bsum, off0, off1);
    fill_prep<<<2048 + 512, 256, 0, stream>>>(idx0, idx1, rankp0, rankp1, off0, off1,
                                              ord0, ord1, Wc0, Wc1, Wb1, Wb2, T0, T1, T2, T3);

    // both eyes in one launch: (2048,2) blocks x 4 waves x 8 segs = 65536 segs/eye
    eye_means_mfma<<<dim3(2048, 2), 256, 0, stream>>>(
        x0, Wr0, br0, off0, ord0, means0,
        x1, Wr1, br1, off1, ord1, means1);

    gemm_wc<<<dim3(512, 2), 256, 0, stream>>>(means0, means1, T0, T1, bc0, bc1, z);
    gemm16<256, 1, 1><<<dim3(512, 2), 256, 0, stream>>>(z,  T2, bb1, hb,  256);
    gemm16<256, 0, 0><<<dim3(512, 1), 256, 0, stream>>>(hb, T3, bb2, out, 128);
}

// Round 19
// 398.903 us; speedup vs baseline: 1.1600x; 1.1600x over previous
//
#include <hip/hip_runtime.h>
#include <hip/hip_bf16.h>

#define B_SEG 65536
#define N_NODES 1048576

typedef _Float16 f16;
typedef __attribute__((ext_vector_type(8))) _Float16 f16x8;
typedef __attribute__((ext_vector_type(2))) __fp16 fp16x2;   // cvt_pkrtz's return type
typedef __attribute__((ext_vector_type(4))) float f32x4;
typedef unsigned short u16;

union F16x8 { f16x8 v; fp16x2 h2[4]; };

#define MFMA16(a, b, acc) __builtin_amdgcn_mfma_f32_16x16x32_f16((a), (b), (acc), 0, 0, 0)

typedef __attribute__((address_space(1))) const void GV;
typedef __attribute__((address_space(3))) void LV;
#define GLOAD_LDS16(g, l) __builtin_amdgcn_global_load_lds((GV*)(g), (LV*)(l), 16, 0, 0)

// ---------------- histogram + rank capture, XCD-partitioned ----------------
__global__ __launch_bounds__(256) void histo_part(const int* __restrict__ idx0,
        const int* __restrict__ idx1, int* __restrict__ cnt0, int* __restrict__ cnt1,
        u16* __restrict__ rankp0, u16* __restrict__ rankp1) {
    int part  = blockIdx.x & 7;
    int chunk = blockIdx.x >> 3;              // 0..255
    u16* r0 = rankp0 + (size_t)part * N_NODES;
    u16* r1 = rankp1 + (size_t)part * N_NODES;
    int base4 = chunk * (N_NODES / 256 / 4);  // 1024 int4-groups per chunk
    for (int g = base4 + threadIdx.x; g < base4 + N_NODES / 256 / 4; g += 256) {
        int4 s0 = ((const int4*)idx0)[g];
        int i = g * 4;
        if ((s0.x >> 13) == part) { int p = atomicAdd(&cnt0[s0.x], 1); r0[i]     = (u16)p; }
        if ((s0.y >> 13) == part) { int p = atomicAdd(&cnt0[s0.y], 1); r0[i + 1] = (u16)p; }
        if ((s0.z >> 13) == part) { int p = atomicAdd(&cnt0[s0.z], 1); r0[i + 2] = (u16)p; }
        if ((s0.w >> 13) == part) { int p = atomicAdd(&cnt0[s0.w], 1); r0[i + 3] = (u16)p; }
        int4 s1 = ((const int4*)idx1)[g];
        if ((s1.x >> 13) == part) { int p = atomicAdd(&cnt1[s1.x], 1); r1[i]     = (u16)p; }
        if ((s1.y >> 13) == part) { int p = atomicAdd(&cnt1[s1.y], 1); r1[i + 1] = (u16)p; }
        if ((s1.z >> 13) == part) { int p = atomicAdd(&cnt1[s1.z], 1); r1[i + 2] = (u16)p; }
        if ((s1.w >> 13) == part) { int p = atomicAdd(&cnt1[s1.w], 1); r1[i + 3] = (u16)p; }
    }
}

// ---------------- 3-stage scan over 2x65536 counters ----------------
__global__ __launch_bounds__(256) void scan1(const int* __restrict__ cnt, int* __restrict__ bsum) {
    int b = blockIdx.x, t = threadIdx.x;
    int4 v = ((const int4*)cnt)[b * 256 + t];
    int s = v.x + v.y + v.z + v.w;
    for (int d = 1; d < 64; d <<= 1) s += __shfl_xor(s, d);
    __shared__ int ws4[4];
    if ((t & 63) == 0) ws4[t >> 6] = s;
    __syncthreads();
    if (t == 0) bsum[b] = ws4[0] + ws4[1] + ws4[2] + ws4[3];
}

__global__ __launch_bounds__(128) void scan2(int* __restrict__ bsum) {
    int t = threadIdx.x, lane = t & 63;
    int v = bsum[t];
    int s = v;
    for (int d = 1; d < 64; d <<= 1) { int u = __shfl_up(s, d); if (lane >= d) s += u; }
    bsum[t] = s - v;
}

__global__ __launch_bounds__(256) void scan3(const int* __restrict__ cnt, const int* __restrict__ bsum,
                                             int* __restrict__ off0, int* __restrict__ off1) {
    int b = blockIdx.x, t = threadIdx.x;
    int4 v = ((const int4*)cnt)[b * 256 + t];
    int local = v.x + v.y + v.z + v.w;
    int lane = t & 63, w = t >> 6;
    int s = local;
    for (int d = 1; d < 64; d <<= 1) { int u = __shfl_up(s, d); if (lane >= d) s += u; }
    __shared__ int wsum[4];
    if (lane == 63) wsum[w] = s;
    __syncthreads();
    int carry = bsum[b];
    for (int i = 0; i < w; ++i) carry += wsum[i];
    int ex = carry + s - local;
    int* off = (b < 64) ? off0 : off1;
    int gi = (b & 63) * 1024 + t * 4;
    off[gi] = ex; ex += v.x; off[gi + 1] = ex; ex += v.y; off[gi + 2] = ex; ex += v.z; off[gi + 3] = ex;
    if (b == 0 && t == 0) { off0[B_SEG] = N_NODES; off1[B_SEG] = N_NODES; }
}

// ---------------- fill CSR (partitioned, zero atomics) + fused weight prep ----------------
__global__ __launch_bounds__(256) void fill_prep(const int* __restrict__ idx0,
        const int* __restrict__ idx1, const u16* __restrict__ rankp0, const u16* __restrict__ rankp1,
        const int* __restrict__ off0, const int* __restrict__ off1,
        int* __restrict__ ord0, int* __restrict__ ord1,
        const float* __restrict__ Wc0, const float* __restrict__ Wc1,
        const float* __restrict__ Wb1, const float* __restrict__ Wb2,
        f16* __restrict__ T0, f16* __restrict__ T1, f16* __restrict__ T2, f16* __restrict__ T3) {
    if (blockIdx.x < 2048) {
        int part  = blockIdx.x & 7;
        int chunk = blockIdx.x >> 3;
        const u16* r0 = rankp0 + (size_t)part * N_NODES;
        const u16* r1 = rankp1 + (size_t)part * N_NODES;
        int base4 = chunk * (N_NODES / 256 / 4);
        for (int g = base4 + threadIdx.x; g < base4 + N_NODES / 256 / 4; g += 256) {
            int4 s0 = ((const int4*)idx0)[g];
            ushort4 q0 = ((const ushort4*)r0)[g];
            int i = g * 4;
            if ((s0.x >> 13) == part) ord0[off0[s0.x] + q0.x] = i;
            if ((s0.y >> 13) == part) ord0[off0[s0.y] + q0.y] = i + 1;
            if ((s0.z >> 13) == part) ord0[off0[s0.z] + q0.z] = i + 2;
            if ((s0.w >> 13) == part) ord0[off0[s0.w] + q0.w] = i + 3;
            int4 s1 = ((const int4*)idx1)[g];
            ushort4 q1 = ((const ushort4*)r1)[g];
            if ((s1.x >> 13) == part) ord1[off1[s1.x] + q1.x] = i;
            if ((s1.y >> 13) == part) ord1[off1[s1.y] + q1.y] = i + 1;
            if ((s1.z >> 13) == part) ord1[off1[s1.z] + q1.z] = i + 2;
            if ((s1.w >> 13) == part) ord1[off1[s1.w] + q1.w] = i + 3;
        }
    } else {
        int b = blockIdx.x - 2048, t = threadIdx.x;
        if (b < 64)        { int i = b * 256 + t;         T0[i] = (f16)Wc0[(i & 127) * 128 + (i >> 7)]; }
        else if (b < 128)  { int i = (b - 64) * 256 + t;  T1[i] = (f16)Wc1[(i & 127) * 128 + (i >> 7)]; }
        else if (b < 384)  { int i = (b - 128) * 256 + t; T2[i] = (f16)Wb1[(i & 255) * 256 + (i >> 8)]; }
        else               { int i = (b - 384) * 256 + t; T3[i] = (f16)Wb2[(i & 255) * 128 + (i >> 8)]; }
    }
}

// ---------------- per-segment mean of relu(x@Wr+br): coalesced-gather MFMA ----------------
// r8 nested-loop body (proven), but the gather is re-mapped for COALESCING:
// lane L fetches row (L>>2), 16B chunk ((L&3)+(row>>1))&3 (swizzled) -- each
// instruction's lane-quads read contiguous 64B of one row => 16 unique lines
// per instruction instead of 64 scattered 16B addresses (the measured ~220us
// invariance across ILP/occupancy/L3-residency says address processing is the
// bottleneck). Data lands in a wave-private 2-slot LDS ring via
// global_load_lds (dest = uniform base + lane*16; swizzle applied on the
// GLOBAL address). Read-back is 2-way bank aliasing (free). Counted vmcnt(4)
// keeps the next batch in flight; rare empty-segment re-prime drains first.
#define SEGS_PER_WAVE 8
__global__ __launch_bounds__(256, 3) void eye_means_mfma(
        const float* __restrict__ xA, const float* __restrict__ WrA, const float* __restrict__ brA,
        const int* __restrict__ offA, const int* __restrict__ ordA, f16* __restrict__ meansA,
        const float* __restrict__ xB, const float* __restrict__ WrB, const float* __restrict__ brB,
        const int* __restrict__ offB, const int* __restrict__ ordB, f16* __restrict__ meansB) {
    const float *x, *Wr, *br; const int *off, *ord; f16* means;
    if (blockIdx.y == 0) { x = xA; Wr = WrA; br = brA; off = offA; ord = ordA; means = meansA; }
    else                 { x = xB; Wr = WrB; br = brB; off = offB; ord = ordB; means = meansB; }

    __shared__ char ldsraw[4][2][4096];
    int lane = threadIdx.x & 63;
    int wv   = threadIdx.x >> 6;
    int wid  = blockIdx.x * 4 + wv;
    int c  = lane & 15;    // A row / C col within tile
    int kq = lane >> 4;    // k-quarter
    char* myslots = &ldsraw[wv][0][0];

    // B fragments: bfr[g][h] covers cols g*16..+15, k = h*32 + kq*8 .. +7
    f16x8 bfr[8][2];
    float rbias[8];
    #pragma unroll
    for (int g = 0; g < 8; ++g) {
        #pragma unroll
        for (int h = 0; h < 2; ++h)
            #pragma unroll
            for (int j = 0; j < 8; ++j)
                bfr[g][h][j] = (f16)Wr[(size_t)(h * 32 + kq * 8 + j) * 128 + g * 16 + c];
        rbias[g] = br[g * 16 + c];
    }

    int s_begin = wid * SEGS_PER_WAVE;
    int offv  = off[s_begin + ((lane <= 8) ? lane : 8)];     // lane i<=8: off[s_begin+i]
    int base0 = __shfl(offv, 0);
    int nxtv  = __shfl(offv, (lane < 8) ? (lane + 1) : 8);
    int szl   = nxtv - offv;             // lanes 0..7: size of segment i

    // pooled CSR preload: entries base0..base0+191 (mean 128, ~5.7 sigma)
    int ov0 = ord[base0 + lane];
    int ov1 = ord[base0 + 64 + lane];
    int ov2 = ord[base0 + 128 + lane];

    // node id for row r of segment at (off_rel, sz). Uniform flow; all shfls
    // full-exec before any select.
    auto node_at = [&](int off_rel, int sz, int r) -> int {
        int e  = off_rel + r;
        int e6 = e & 63;
        int n0 = __shfl(ov0, e6);
        int n1 = __shfl(ov1, e6);
        int n2 = __shfl(ov2, e6);
        int n  = (e < 64) ? n0 : (e < 128) ? n1 : n2;
        if (e >= 192) n = ord[base0 + e];   // ord padded: always legal
        return (r < sz) ? n : 0;            // padded row -> node 0 (safe address)
    };

    // issue batch b2 of segment (off_rel2, sz2) into LDS slot (4 coalesced insts)
    int lrow = lane >> 2;                    // row this lane fetches
    int lq   = lane & 3;                     // lds chunk position
    int lqg  = (lq + (lrow >> 1)) & 3;       // swizzled global chunk
    auto issue_batch = [&](int off_rel2, int sz2, int b2, int slot) {
        int node = node_at(off_rel2, sz2, b2 * 16 + lrow);
        const float* gp = x + (size_t)node * 64 + lqg * 4;
        char* lb = myslots + slot * 4096;
        GLOAD_LDS16(gp,      lb);            // h=0: row bytes 0..63
        GLOAD_LDS16(gp + 16, lb + 1024);     // h=1: bytes 64..127
        GLOAD_LDS16(gp + 32, lb + 2048);     // h=2: bytes 128..191
        GLOAD_LDS16(gp + 48, lb + 3072);     // h=3: bytes 192..255
    };

    float sum[8];
    #pragma unroll
    for (int g = 0; g < 8; ++g) sum[g] = 0.f;
    const f16x8 zf = {};

    // reader offsets: lane (c,kq) wants row c, chunks qg=(kq&1)*2, +1 at
    // h1=kq>>1 and h2=h1+2; lds position q' = (qg - (c>>1)) & 3.
    int h1o = (kq >> 1) * 1024 + c * 64;
    int q1o = ((((kq & 1) * 2)     - (c >> 1)) & 3) * 16;
    int q2o = ((((kq & 1) * 2 + 1) - (c >> 1)) & 3) * 16;

    auto compute_batch = [&](int slot, int b2, int sz2) {
        const char* lb = myslots + slot * 4096;
        float4 va = *(const float4*)(lb + h1o + q1o);
        float4 vb = *(const float4*)(lb + h1o + q2o);
        float4 vc = *(const float4*)(lb + 2048 + h1o + q1o);
        float4 vd = *(const float4*)(lb + 2048 + h1o + q2o);
        f16x8 A0 = zf, A1 = zf;
        if (b2 * 16 + c < sz2) {
            F16x8 u0, u1;
            u0.h2[0] = __builtin_amdgcn_cvt_pkrtz(va.x, va.y);
            u0.h2[1] = __builtin_amdgcn_cvt_pkrtz(va.z, va.w);
            u0.h2[2] = __builtin_amdgcn_cvt_pkrtz(vb.x, vb.y);
            u0.h2[3] = __builtin_amdgcn_cvt_pkrtz(vb.z, vb.w);
            u1.h2[0] = __builtin_amdgcn_cvt_pkrtz(vc.x, vc.y);
            u1.h2[1] = __builtin_amdgcn_cvt_pkrtz(vc.z, vc.w);
            u1.h2[2] = __builtin_amdgcn_cvt_pkrtz(vd.x, vd.y);
            u1.h2[3] = __builtin_amdgcn_cvt_pkrtz(vd.z, vd.w);
            A0 = u0.v; A1 = u1.v;
        }
        #pragma unroll
        for (int g = 0; g < 8; ++g) {
            f32x4 acc = {0.f, 0.f, 0.f, 0.f};
            acc = MFMA16(A0, bfr[g][0], acc);
            acc = MFMA16(A1, bfr[g][1], acc);
            #pragma unroll
            for (int r = 0; r < 4; ++r)
                sum[g] += fmaxf(acc[r] + rbias[g], 0.f);   // relu BEFORE segment sum
        }
    };

    // prime: segment 0 batch 0 -> slot 0
    {
        int sz0 = __shfl(szl, 0);
        issue_batch(0, sz0, 0, 0);
    }
    int cur = 0;

    #pragma unroll
    for (int s = 0; s < SEGS_PER_WAVE; ++s) {
        int off_rel   = __shfl(offv, s) - base0;
        int sz        = __shfl(szl, s);
        int nb        = (sz + 15) >> 4;
        int off_rel_n = (s < SEGS_PER_WAVE - 1) ? (__shfl(offv, s + 1) - base0) : 0;
        int sz_n      = (s < SEGS_PER_WAVE - 1) ? __shfl(szl, s + 1) : 0;
        size_t mb     = (size_t)(s_begin + s) * 128;

        if (nb == 0) {                       // empty segment: zero means, re-prime cur
            means[mb + (2 * kq + 0) * 16 + c] = (f16)0.f;
            means[mb + (2 * kq + 1) * 16 + c] = (f16)0.f;
            asm volatile("s_waitcnt vmcnt(0)" ::: "memory");   // avoid same-dest DMA race
            __builtin_amdgcn_sched_barrier(0);
            issue_batch(off_rel_n, sz_n, 0, cur);
            continue;
        }

        for (int b = 0; b < nb; ++b) {
            int nxt = cur ^ 1;
            if (b + 1 < nb) issue_batch(off_rel, sz, b + 1, nxt);
            else            issue_batch(off_rel_n, sz_n, 0, nxt);
            asm volatile("s_waitcnt vmcnt(4)" ::: "memory");   // cur slot's 4 loads done
            __builtin_amdgcn_sched_barrier(0);
            compute_batch(cur, b, sz);
            cur = nxt;
        }

        // flush segment s
        float padc = (float)(nb * 16 - sz);
        float inv  = 1.f / (float)sz;
        #pragma unroll
        for (int g = 0; g < 8; ++g) {
            float v = sum[g];
            v += __shfl_xor(v, 16);
            v += __shfl_xor(v, 32);
            v -= padc * fmaxf(rbias[g], 0.f);   // padded rows contributed relu(bias)
            sum[g] = v * inv;
        }
        means[mb + (2 * kq + 0) * 16 + c] = (f16)sum[2 * kq + 0];
        means[mb + (2 * kq + 1) * 16 + c] = (f16)sum[2 * kq + 1];
        #pragma unroll
        for (int g = 0; g < 8; ++g) sum[g] = 0.f;
    }
}

// ---------------- f16 MFMA GEMM, zero-LDS ----------------
template<int K, int RELU, int OUT16>
__global__ __launch_bounds__(256) void gemm16(
        const f16* __restrict__ A, const f16* __restrict__ BT,
        const float* __restrict__ bias, void* __restrict__ Cv, int ldc) {
    int lane = threadIdx.x & 63;
    int w = threadIdx.x >> 6;
    int c = lane & 15, kq = lane >> 4;
    int m0 = blockIdx.x * 128 + w * 32;
    int n0 = blockIdx.y * 128;

    f32x4 acc[2][8] = {};
    const f16* arow0 = A + (size_t)(m0 + c) * K + kq * 8;
    const f16* arow1 = arow0 + (size_t)16 * K;
    const f16* brow  = BT + (size_t)(n0 + c) * K + kq * 8;

    #pragma unroll 2
    for (int k0 = 0; k0 < K; k0 += 32) {
        f16x8 a0 = *(const f16x8*)(arow0 + k0);
        f16x8 a1 = *(const f16x8*)(arow1 + k0);
        #pragma unroll
        for (int g = 0; g < 8; ++g) {
            f16x8 bf = *(const f16x8*)(brow + (size_t)g * 16 * K + k0);
            acc[0][g] = MFMA16(a0, bf, acc[0][g]);
            acc[1][g] = MFMA16(a1, bf, acc[1][g]);
        }
    }

    #pragma unroll
    for (int g = 0; g < 8; ++g) {
        float bv = bias[n0 + g * 16 + c];
        #pragma unroll
        for (int ms = 0; ms < 2; ++ms) {
            #pragma unroll
            for (int r = 0; r < 4; ++r) {
                float v = acc[ms][g][r] + bv;
                if (RELU) v = fmaxf(v, 0.f);
                size_t ci = (size_t)(m0 + ms * 16 + kq * 4 + r) * ldc + n0 + g * 16 + c;
                if (OUT16) ((f16*)Cv)[ci] = (f16)v;
                else       ((float*)Cv)[ci] = v;
            }
        }
    }
}

// Wc stage for both eyes in one launch
__global__ __launch_bounds__(256) void gemm_wc(
        const f16* __restrict__ M0, const f16* __restrict__ M1,
        const f16* __restrict__ T0, const f16* __restrict__ T1,
        const float* __restrict__ bc0, const float* __restrict__ bc1,
        f16* __restrict__ z) {
    int e = blockIdx.y;
    const f16* A  = e ? M1 : M0;
    const f16* BT = e ? T1 : T0;
    const float* bias = e ? bc1 : bc0;
    int lane = threadIdx.x & 63;
    int w = threadIdx.x >> 6;
    int c = lane & 15, kq = lane >> 4;
    int m0 = blockIdx.x * 128 + w * 32;

    f32x4 acc[2][8] = {};
    const f16* arow0 = A + (size_t)(m0 + c) * 128 + kq * 8;
    const f16* arow1 = arow0 + (size_t)16 * 128;
    const f16* brow  = BT + (size_t)c * 128 + kq * 8;

    #pragma unroll
    for (int k0 = 0; k0 < 128; k0 += 32) {
        f16x8 a0 = *(const f16x8*)(arow0 + k0);
        f16x8 a1 = *(const f16x8*)(arow1 + k0);
        #pragma unroll
        for (int g = 0; g < 8; ++g) {
            f16x8 bf = *(const f16x8*)(brow + (size_t)g * 16 * 128 + k0);
            acc[0][g] = MFMA16(a0, bf, acc[0][g]);
            acc[1][g] = MFMA16(a1, bf, acc[1][g]);
        }
    }

    #pragma unroll
    for (int g = 0; g < 8; ++g) {
        float bv = bias[g * 16 + c];
        #pragma unroll
        for (int ms = 0; ms < 2; ++ms) {
            #pragma unroll
            for (int r = 0; r < 4; ++r) {
                float v = fmaxf(acc[ms][g][r] + bv, 0.f);
                z[(size_t)(m0 + ms * 16 + kq * 4 + r) * 256 + e * 128 + g * 16 + c] = (f16)v;
            }
        }
    }
}

extern "C" void kernel_launch(void* const* d_in, const int* in_sizes, int n_in,
                              void* d_out, int out_size, void* d_ws, size_t ws_size,
                              hipStream_t stream) {
    const float* x0  = (const float*)d_in[0];
    const float* x1  = (const float*)d_in[1];
    const int*   idx0 = (const int*)d_in[2];
    const int*   idx1 = (const int*)d_in[3];
    const float* Wr0 = (const float*)d_in[4];
    const float* br0 = (const float*)d_in[5];
    const float* Wc0 = (const float*)d_in[6];
    const float* bc0 = (const float*)d_in[7];
    const float* Wr1 = (const float*)d_in[8];
    const float* br1 = (const float*)d_in[9];
    const float* Wc1 = (const float*)d_in[10];
    const float* bc1 = (const float*)d_in[11];
    const float* Wb1 = (const float*)d_in[12];
    const float* bb1 = (const float*)d_in[13];
    const float* Wb2 = (const float*)d_in[14];
    const float* bb2 = (const float*)d_in[15];
    float* out = (float*)d_out;

    char* w = (char*)d_ws;
    auto alloc = [&](size_t bytes) { void* p = (void*)w; w += (bytes + 255) & ~(size_t)255; return p; };
    int* cnt0 = (int*)alloc((size_t)B_SEG * 4);
    int* cnt1 = (int*)alloc((size_t)B_SEG * 4);
    int* off0 = (int*)alloc((size_t)(B_SEG + 1) * 4);
    int* off1 = (int*)alloc((size_t)(B_SEG + 1) * 4);
    int* ord0 = (int*)alloc((size_t)(N_NODES + 4096) * 4);   // pad for pool fallback
    int* ord1 = (int*)alloc((size_t)(N_NODES + 4096) * 4);
    u16* rankp0 = (u16*)alloc((size_t)8 * N_NODES * 2);      // per-partition rank slices
    u16* rankp1 = (u16*)alloc((size_t)8 * N_NODES * 2);
    int* bsum = (int*)alloc(128 * 4);
    f16* means0 = (f16*)alloc((size_t)B_SEG * 128 * 2);
    f16* means1 = (f16*)alloc((size_t)B_SEG * 128 * 2);
    f16* z      = (f16*)alloc((size_t)B_SEG * 256 * 2);
    f16* hb     = (f16*)alloc((size_t)B_SEG * 256 * 2);
    f16* T0     = (f16*)alloc((size_t)128 * 128 * 2);
    f16* T1     = (f16*)alloc((size_t)128 * 128 * 2);
    f16* T2     = (f16*)alloc((size_t)256 * 256 * 2);
    f16* T3     = (f16*)alloc((size_t)128 * 256 * 2);

    (void)hipMemsetAsync(cnt0, 0, 2 * (size_t)B_SEG * sizeof(int), stream);
    histo_part<<<2048, 256, 0, stream>>>(idx0, idx1, cnt0, cnt1, rankp0, rankp1);
    scan1<<<128, 256, 0, stream>>>(cnt0, bsum);
    scan2<<<1, 128, 0, stream>>>(bsum);
    scan3<<<128, 256, 0, stream>>>(cnt0, bsum, off0, off1);
    fill_prep<<<2048 + 512, 256, 0, stream>>>(idx0, idx1, rankp0, rankp1, off0, off1,
                                              ord0, ord1, Wc0, Wc1, Wb1, Wb2, T0, T1, T2, T3);

    // both eyes in one launch: (2048,2) blocks x 4 waves x 8 segs = 65536 segs/eye
    eye_means_mfma<<<dim3(2048, 2), 256, 0, stream>>>(
        x0, Wr0, br0, off0, ord0, means0,
        x1, Wr1, br1, off1, ord1, means1);

    gemm_wc<<<dim3(512, 2), 256, 0, stream>>>(means0, means1, T0, T1, bc0, bc1, z);
    gemm16<256, 1, 1><<<dim3(512, 2), 256, 0, stream>>>(z,  T2, bb1, hb,  256);
    gemm16<256, 0, 0><<<dim3(512, 1), 256, 0, stream>>>(hb, T3, bb2, out, 128);
}